// Round 1
// baseline (272.609 us; speedup 1.0000x reference)
//
#include <hip/hip_runtime.h>

// Problem constants (match reference)
constexpr int BB  = 8;
constexpr int NN  = 2048;
constexpr int IND = 128;
constexpr int HD  = 64;
constexpr float LN_EPS = 1e-5f;
constexpr float SLOPE  = 0.2f;

typedef _Float16 half8 __attribute__((ext_vector_type(8)));
typedef float    f32x4 __attribute__((ext_vector_type(4)));

__device__ __forceinline__ float wave_sum(float v) {
    #pragma unroll
    for (int off = 32; off > 0; off >>= 1) v += __shfl_xor(v, off);
    return v;
}
__device__ __forceinline__ float wave_max(float v) {
    #pragma unroll
    for (int off = 32; off > 0; off >>= 1) v = fmaxf(v, __shfl_xor(v, off));
    return v;
}

// ---------------------------------------------------------------------------
// Kernel 1: gated inputs.  One wave handles 8 rows (register tile) so each
// coalesced weight load (lane = output column) is amortized over 8 rows.
// Produces: Wh (f32, second output), Whh (fp16 copy for MFMA), Wh1, Wh2.
// ---------------------------------------------------------------------------
__global__ __launch_bounds__(256) void k_gates(
    const float* __restrict__ x, const float* __restrict__ h,
    const float* __restrict__ X2H, const float* __restrict__ H2H,
    const float* __restrict__ a,
    float* __restrict__ Wh_out, _Float16* __restrict__ Whh,
    float* __restrict__ Wh1, float* __restrict__ Wh2)
{
    const int lane = threadIdx.x & 63;
    const int wid  = threadIdx.x >> 6;
    const int base = (blockIdx.x * 4 + wid) * 8;   // 8 rows per wave

    float gx0[8] = {0}, gx1[8] = {0}, gx2[8] = {0};
    float gh0[8] = {0}, gh1[8] = {0}, gh2[8] = {0};

    // x @ X2H  (IND=128 reduction)
    for (int d4 = 0; d4 < IND; d4 += 4) {
        float w0[4], w1[4], w2[4];
        #pragma unroll
        for (int dd = 0; dd < 4; ++dd) {
            const float* wp = X2H + (size_t)(d4 + dd) * 192;
            w0[dd] = wp[lane]; w1[dd] = wp[64 + lane]; w2[dd] = wp[128 + lane];
        }
        #pragma unroll
        for (int rr = 0; rr < 8; ++rr) {
            f32x4 xv = *(const f32x4*)(x + (size_t)(base + rr) * IND + d4);
            #pragma unroll
            for (int dd = 0; dd < 4; ++dd) {
                gx0[rr] = fmaf(xv[dd], w0[dd], gx0[rr]);
                gx1[rr] = fmaf(xv[dd], w1[dd], gx1[rr]);
                gx2[rr] = fmaf(xv[dd], w2[dd], gx2[rr]);
            }
        }
    }
    // h @ H2H  (HD=64 reduction)
    for (int d4 = 0; d4 < HD; d4 += 4) {
        float w0[4], w1[4], w2[4];
        #pragma unroll
        for (int dd = 0; dd < 4; ++dd) {
            const float* wp = H2H + (size_t)(d4 + dd) * 192;
            w0[dd] = wp[lane]; w1[dd] = wp[64 + lane]; w2[dd] = wp[128 + lane];
        }
        #pragma unroll
        for (int rr = 0; rr < 8; ++rr) {
            f32x4 hv = *(const f32x4*)(h + (size_t)(base + rr) * HD + d4);
            #pragma unroll
            for (int dd = 0; dd < 4; ++dd) {
                gh0[rr] = fmaf(hv[dd], w0[dd], gh0[rr]);
                gh1[rr] = fmaf(hv[dd], w1[dd], gh1[rr]);
                gh2[rr] = fmaf(hv[dd], w2[dd], gh2[rr]);
            }
        }
    }

    const float a0 = a[lane], a1 = a[64 + lane];
    for (int rr = 0; rr < 8; ++rr) {
        const int row = base + rr;
        const float hr = h[(size_t)row * HD + lane];
        const float rg = 1.f / (1.f + __expf(-(gx0[rr] + gh0[rr])));
        const float ig = 1.f / (1.f + __expf(-(gx1[rr] + gh1[rr])));
        float irh = gx2[rr] + rg * gh2[rr];
        const float mu = wave_sum(irh) * (1.f / 64.f);
        const float dv = irh - mu;
        const float var = wave_sum(dv * dv) * (1.f / 64.f);
        const float ng = tanhf(dv * rsqrtf(var + LN_EPS));
        const float wh = ng + ig * (hr - ng);
        Wh_out[(size_t)row * HD + lane] = wh;
        Whh[(size_t)row * HD + lane] = (_Float16)wh;
        const float d1 = wave_sum(wh * a0);
        const float d2 = wave_sum(wh * a1);
        if (lane == 0) { Wh1[row] = d1; Wh2[row] = d2; }
    }
}

// ---------------------------------------------------------------------------
// Kernel 2: masked softmax attention + P@Wh via MFMA.
// One block = 16 query rows.  Phase A: scores + softmax, store P (fp16) in
// LDS [16][2048+8] (pad 8 breaks the 4KB row-stride bank aliasing for the
// b128 A-fragment reads).  Phase B: 4 waves, each one 16-wide d-chunk,
// K=2048 via 64 x mfma_f32_16x16x32_f16.
// ---------------------------------------------------------------------------
constexpr int PSTR = NN + 8;   // fp16 elements per P row

__global__ __launch_bounds__(256) void k_attn(
    const int* __restrict__ adj,
    const _Float16* __restrict__ Whh,
    const float* __restrict__ Wh1, const float* __restrict__ Wh2,
    float* __restrict__ hp)
{
    __shared__ float Wh2s[NN];
    __shared__ __align__(16) _Float16 Pbuf[16 * PSTR];
    __shared__ float redbuf[4];
    __shared__ float lsum[16];
    __shared__ float wh1s[16];

    const int tid  = threadIdx.x;
    const int lane = tid & 63;
    const int wid  = tid >> 6;
    const int b    = blockIdx.x >> 7;          // NN/16 = 128 tiles per batch
    const int i0   = (blockIdx.x & 127) * 16;

    for (int j = tid; j < NN; j += 256) Wh2s[j] = Wh2[b * NN + j];
    if (tid < 16) wh1s[tid] = Wh1[b * NN + i0 + tid];
    __syncthreads();

    // ---- Phase A: scores + softmax, P into LDS ----
    for (int r = 0; r < 16; ++r) {
        const int row = i0 + r;
        const float w1 = wh1s[r];
        const int* __restrict__ arow = adj + ((size_t)b * NN + row) * NN;

        float s[8];
        float mx = -3e38f;
        #pragma unroll
        for (int k = 0; k < 8; ++k) {
            const int j = tid + k * 256;
            const int av = arow[j];
            const float t = w1 + Wh2s[j];
            const float e = (t > 0.f) ? t : SLOPE * t;
            s[k] = av ? e : -1e30f;              // exp underflows to 0
            mx = fmaxf(mx, s[k]);
        }
        mx = wave_max(mx);
        __syncthreads();                          // redbuf reuse guard
        if (lane == 0) redbuf[wid] = mx;
        __syncthreads();
        mx = fmaxf(fmaxf(redbuf[0], redbuf[1]), fmaxf(redbuf[2], redbuf[3]));

        float sum = 0.f;
        #pragma unroll
        for (int k = 0; k < 8; ++k) {
            const int j = tid + k * 256;
            const float p = __expf(s[k] - mx);
            sum += p;
            Pbuf[r * PSTR + j] = (_Float16)p;
        }
        sum = wave_sum(sum);
        __syncthreads();                          // redbuf reuse guard
        if (lane == 0) redbuf[wid] = sum;
        __syncthreads();
        if (tid == 0) lsum[r] = redbuf[0] + redbuf[1] + redbuf[2] + redbuf[3];
    }
    __syncthreads();

    // ---- Phase B: h'[16 x 64] = P[16 x 2048] @ Wh[2048 x 64] (MFMA) ----
    const int n0 = wid * 16;        // d-chunk per wave
    const int m  = lane & 15;       // A row / B col / D col
    const int q  = lane >> 4;       // quad
    const _Float16* __restrict__ Wb = Whh + (size_t)b * NN * HD;

    f32x4 acc = {0.f, 0.f, 0.f, 0.f};
    for (int k0 = 0; k0 < NN; k0 += 32) {
        const int kq = k0 + q * 8;
        const half8 av = *(const half8*)(&Pbuf[m * PSTR + kq]);   // ds_read_b128
        half8 bv;
        #pragma unroll
        for (int jj = 0; jj < 8; ++jj)
            bv[jj] = Wb[(size_t)(kq + jj) * HD + n0 + m];
        acc = __builtin_amdgcn_mfma_f32_16x16x32_f16(av, bv, acc, 0, 0, 0);
    }
    #pragma unroll
    for (int r2 = 0; r2 < 4; ++r2) {
        const int irow = q * 4 + r2;              // D row = quad*4 + reg
        const float inv = 1.f / lsum[irow];
        hp[((size_t)b * NN + i0 + irow) * HD + n0 + m] = acc[r2] * inv;
    }
}

// ---------------------------------------------------------------------------
extern "C" void kernel_launch(void* const* d_in, const int* in_sizes, int n_in,
                              void* d_out, int out_size, void* d_ws, size_t ws_size,
                              hipStream_t stream) {
    const int*   adj = (const int*)d_in[0];
    const float* x   = (const float*)d_in[1];
    const float* h   = (const float*)d_in[2];
    const float* X2H = (const float*)d_in[3];
    const float* H2H = (const float*)d_in[4];
    const float* a   = (const float*)d_in[5];

    float* out = (float*)d_out;
    float* hp  = out;                              // h_prime [8][2048][64]
    float* Wh  = out + (size_t)BB * NN * HD;       // Wh      [8][2048][64]

    float*    Wh1 = (float*)d_ws;                  // [B*N]
    float*    Wh2 = Wh1 + BB * NN;                 // [B*N]
    _Float16* Whh = (_Float16*)(Wh2 + BB * NN);    // [B*N][64] fp16 copy

    k_gates<<<dim3((BB * NN) / 32), dim3(256), 0, stream>>>(
        x, h, X2H, H2H, a, Wh, Whh, Wh1, Wh2);
    k_attn<<<dim3(BB * (NN / 16)), dim3(256), 0, stream>>>(
        adj, Whh, Wh1, Wh2, hp);
}

// Round 2
// 259.007 us; speedup vs baseline: 1.0525x; 1.0525x over previous
//
#include <hip/hip_runtime.h>

// Problem constants (match reference)
constexpr int BB  = 8;
constexpr int NN  = 2048;
constexpr int IND = 128;
constexpr int HD  = 64;
constexpr float LN_EPS = 1e-5f;
constexpr float SLOPE  = 0.2f;

typedef _Float16 half8 __attribute__((ext_vector_type(8)));
typedef _Float16 half4 __attribute__((ext_vector_type(4)));
typedef float    f32x4 __attribute__((ext_vector_type(4)));

__device__ __forceinline__ float wave_sum(float v) {
    #pragma unroll
    for (int off = 32; off > 0; off >>= 1) v += __shfl_xor(v, off);
    return v;
}
__device__ __forceinline__ float wave_max(float v) {
    #pragma unroll
    for (int off = 32; off > 0; off >>= 1) v = fmaxf(v, __shfl_xor(v, off));
    return v;
}

// ---------------------------------------------------------------------------
// Kernel 1: gated inputs.  One wave handles 8 rows (register tile) so each
// coalesced weight load (lane = output column) is amortized over 8 rows.
// Produces: Wh (f32, second output), Whh2 (fp16, k-packed-by-8 layout
// [B][N/8][64][8] so the MFMA B-fragment is one dwordx4), Wh1, Wh2.
// ---------------------------------------------------------------------------
__global__ __launch_bounds__(256) void k_gates(
    const float* __restrict__ x, const float* __restrict__ h,
    const float* __restrict__ X2H, const float* __restrict__ H2H,
    const float* __restrict__ a,
    float* __restrict__ Wh_out, _Float16* __restrict__ Whh2,
    float* __restrict__ Wh1, float* __restrict__ Wh2)
{
    const int lane = threadIdx.x & 63;
    const int wid  = threadIdx.x >> 6;
    const int base = (blockIdx.x * 4 + wid) * 8;   // 8 rows per wave (one k-pack)

    float gx0[8] = {0}, gx1[8] = {0}, gx2[8] = {0};
    float gh0[8] = {0}, gh1[8] = {0}, gh2[8] = {0};

    // x @ X2H  (IND=128 reduction)
    for (int d4 = 0; d4 < IND; d4 += 4) {
        float w0[4], w1[4], w2[4];
        #pragma unroll
        for (int dd = 0; dd < 4; ++dd) {
            const float* wp = X2H + (size_t)(d4 + dd) * 192;
            w0[dd] = wp[lane]; w1[dd] = wp[64 + lane]; w2[dd] = wp[128 + lane];
        }
        #pragma unroll
        for (int rr = 0; rr < 8; ++rr) {
            f32x4 xv = *(const f32x4*)(x + (size_t)(base + rr) * IND + d4);
            #pragma unroll
            for (int dd = 0; dd < 4; ++dd) {
                gx0[rr] = fmaf(xv[dd], w0[dd], gx0[rr]);
                gx1[rr] = fmaf(xv[dd], w1[dd], gx1[rr]);
                gx2[rr] = fmaf(xv[dd], w2[dd], gx2[rr]);
            }
        }
    }
    // h @ H2H  (HD=64 reduction)
    for (int d4 = 0; d4 < HD; d4 += 4) {
        float w0[4], w1[4], w2[4];
        #pragma unroll
        for (int dd = 0; dd < 4; ++dd) {
            const float* wp = H2H + (size_t)(d4 + dd) * 192;
            w0[dd] = wp[lane]; w1[dd] = wp[64 + lane]; w2[dd] = wp[128 + lane];
        }
        #pragma unroll
        for (int rr = 0; rr < 8; ++rr) {
            f32x4 hv = *(const f32x4*)(h + (size_t)(base + rr) * HD + d4);
            #pragma unroll
            for (int dd = 0; dd < 4; ++dd) {
                gh0[rr] = fmaf(hv[dd], w0[dd], gh0[rr]);
                gh1[rr] = fmaf(hv[dd], w1[dd], gh1[rr]);
                gh2[rr] = fmaf(hv[dd], w2[dd], gh2[rr]);
            }
        }
    }

    const float a0 = a[lane], a1 = a[64 + lane];
    half8 p8;
    for (int rr = 0; rr < 8; ++rr) {
        const int row = base + rr;
        const float hr = h[(size_t)row * HD + lane];
        const float rg = 1.f / (1.f + __expf(-(gx0[rr] + gh0[rr])));
        const float ig = 1.f / (1.f + __expf(-(gx1[rr] + gh1[rr])));
        float irh = gx2[rr] + rg * gh2[rr];
        const float mu = wave_sum(irh) * (1.f / 64.f);
        const float dv = irh - mu;
        const float var = wave_sum(dv * dv) * (1.f / 64.f);
        const float ng = tanhf(dv * rsqrtf(var + LN_EPS));
        const float wh = ng + ig * (hr - ng);
        Wh_out[(size_t)row * HD + lane] = wh;
        p8[rr] = (_Float16)wh;
        const float d1 = wave_sum(wh * a0);
        const float d2 = wave_sum(wh * a1);
        if (lane == 0) { Wh1[row] = d1; Wh2[row] = d2; }
    }
    // k-packed store: [row-pack base>>3][n=lane][k&7] — one 16B store, 1KB/wave
    *(half8*)(Whh2 + ((size_t)(base >> 3) * 64 + lane) * 8) = p8;
}

// ---------------------------------------------------------------------------
// Kernel 2: masked softmax attention + P@Wh via MFMA.
// One block = 16 query rows, 4 waves; each wave owns 4 rows end-to-end.
// No per-row block barriers: softmax shift c = lrelu(Wh1_row + max_j Wh2)
// is an exact per-row upper bound (lrelu monotone), so no max pass and no
// cross-wave reduction per row.  P (fp16) goes to LDS only for the
// C-layout -> A-layout transform into the MFMA.
// ---------------------------------------------------------------------------
constexpr int PSTR = NN + 8;   // fp16 elements per P row (16B-aligned rows)

__global__ __launch_bounds__(256) void k_attn(
    const int* __restrict__ adj,
    const _Float16* __restrict__ Whh2,   // [B][N/8][64][8]
    const float* __restrict__ Wh1, const float* __restrict__ Wh2,
    float* __restrict__ hp)
{
    __shared__ __align__(16) _Float16 Pbuf[16 * PSTR];
    __shared__ float redbuf[4];
    __shared__ float lsum[16];

    const int tid  = threadIdx.x;
    const int lane = tid & 63;
    const int wid  = tid >> 6;
    const int b    = blockIdx.x >> 7;          // NN/16 = 128 tiles per batch
    const int i0   = (blockIdx.x & 127) * 16;

    // Register-cache this wave's 32 Wh2 columns (shared by its 4 rows)
    f32x4 wv[8];
    const f32x4* __restrict__ w2v = (const f32x4*)(Wh2 + (size_t)b * NN);
    #pragma unroll
    for (int k = 0; k < 8; ++k) wv[k] = w2v[lane + 64 * k];

    // batch-wide max of Wh2 (one block-reduction, the only pre-barrier)
    float mx = -3e38f;
    #pragma unroll
    for (int k = 0; k < 8; ++k)
        mx = fmaxf(mx, fmaxf(fmaxf(wv[k][0], wv[k][1]), fmaxf(wv[k][2], wv[k][3])));
    mx = wave_max(mx);
    if (lane == 0) redbuf[wid] = mx;
    __syncthreads();
    const float M = fmaxf(fmaxf(redbuf[0], redbuf[1]), fmaxf(redbuf[2], redbuf[3]));

    // ---- Phase A: each wave processes rows wid*4 .. wid*4+3, barrier-free
    const int4* __restrict__ atile = (const int4*)(adj + ((size_t)b * NN + i0) * NN);
    #pragma unroll
    for (int rr = 0; rr < 4; ++rr) {
        const int r = wid * 4 + rr;
        const float w1 = Wh1[b * NN + i0 + r];
        const float t0 = w1 + M;
        const float c  = (t0 > 0.f) ? t0 : SLOPE * t0;   // exact row upper bound
        const int4* __restrict__ arow = atile + (size_t)r * (NN / 4);

        int4 av[8];
        #pragma unroll
        for (int k = 0; k < 8; ++k) av[k] = arow[lane + 64 * k];   // 8 in flight

        float sum = 0.f;
        #pragma unroll
        for (int k = 0; k < 8; ++k) {
            const int ai[4] = {av[k].x, av[k].y, av[k].z, av[k].w};
            half4 ph;
            #pragma unroll
            for (int d = 0; d < 4; ++d) {
                const float t = w1 + wv[k][d];
                const float e = (t > 0.f) ? t : SLOPE * t;
                const float p = ai[d] ? __expf(e - c) : 0.f;
                sum += p;
                ph[d] = (_Float16)p;
            }
            *(half4*)&Pbuf[r * PSTR + 4 * (lane + 64 * k)] = ph;  // ds_write_b64
        }
        sum = wave_sum(sum);
        if (lane == 0) lsum[r] = sum;   // row owned by this wave: no race
    }
    __syncthreads();

    // ---- Phase B: h'[16 x 64] = P[16 x 2048] @ Wh[2048 x 64] (MFMA) ----
    const int n0 = wid * 16;        // d-chunk per wave
    const int m  = lane & 15;       // A row / B col / D col
    const int q  = lane >> 4;       // quad
    const half8* __restrict__ Wp = (const half8*)(Whh2 + (size_t)b * NN * HD);
    const _Float16* __restrict__ prow = &Pbuf[m * PSTR];

    f32x4 acc = {0.f, 0.f, 0.f, 0.f};
    #pragma unroll 4
    for (int k0 = 0; k0 < NN; k0 += 32) {
        const half8 av = *(const half8*)(prow + k0 + q * 8);      // ds_read_b128
        const half8 bv = Wp[((k0 >> 3) + q) * 64 + n0 + m];       // dwordx4, 256B/quad
        acc = __builtin_amdgcn_mfma_f32_16x16x32_f16(av, bv, acc, 0, 0, 0);
    }
    #pragma unroll
    for (int r2 = 0; r2 < 4; ++r2) {
        const int irow = q * 4 + r2;              // D row = quad*4 + reg
        const float inv = 1.f / lsum[irow];
        hp[((size_t)b * NN + i0 + irow) * HD + n0 + m] = acc[r2] * inv;
    }
}

// ---------------------------------------------------------------------------
extern "C" void kernel_launch(void* const* d_in, const int* in_sizes, int n_in,
                              void* d_out, int out_size, void* d_ws, size_t ws_size,
                              hipStream_t stream) {
    const int*   adj = (const int*)d_in[0];
    const float* x   = (const float*)d_in[1];
    const float* h   = (const float*)d_in[2];
    const float* X2H = (const float*)d_in[3];
    const float* H2H = (const float*)d_in[4];
    const float* a   = (const float*)d_in[5];

    float* out = (float*)d_out;
    float* hp  = out;                              // h_prime [8][2048][64]
    float* Wh  = out + (size_t)BB * NN * HD;       // Wh      [8][2048][64]

    float*    Wh1  = (float*)d_ws;                 // [B*N]
    float*    Wh2  = Wh1 + BB * NN;                // [B*N]
    _Float16* Whh2 = (_Float16*)(Wh2 + BB * NN);   // [B][N/8][64][8] fp16

    k_gates<<<dim3((BB * NN) / 32), dim3(256), 0, stream>>>(
        x, h, X2H, H2H, a, Wh, Whh2, Wh1, Wh2);
    k_attn<<<dim3(BB * (NN / 16)), dim3(256), 0, stream>>>(
        adj, Whh2, Wh1, Wh2, hp);
}